// Round 3
// baseline (1184.570 us; speedup 1.0000x reference)
//
#include <hip/hip_runtime.h>
#include <hip/hip_bf16.h>
#include <cstddef>

#define N_NODES 100000
#define E_EDGES 1600000
#define TOT_EDGES (E_EDGES + N_NODES)
#define NEG_SLOPE 0.2f
#define BN_EPS 1e-5f

typedef __attribute__((ext_vector_type(8))) short short8;
typedef __attribute__((ext_vector_type(4))) float f32x4;

__device__ __forceinline__ unsigned short f2bf(float f) {
    union { float f; unsigned u; } c; c.f = f;
    unsigned u = c.u;
    u += 0x7fffu + ((u >> 16) & 1u);
    return (unsigned short)(u >> 16);
}
__device__ __forceinline__ float bf2f(unsigned short h) {
    union { unsigned u; float f; } c; c.u = ((unsigned)h) << 16;
    return c.f;
}
__device__ __forceinline__ float bflo(unsigned u) {
    union { unsigned u; float f; } c; c.u = u << 16; return c.f;
}
__device__ __forceinline__ float bfhi(unsigned u) {
    union { unsigned u; float f; } c; c.u = u & 0xffff0000u; return c.f;
}
__device__ __forceinline__ float lrelu(float t) {
    return (t > 0.f) ? t : NEG_SLOPE * t;
}

// ---------------------------------------------------------------------------
// CSR build
// ---------------------------------------------------------------------------

__global__ __launch_bounds__(256) void count_kernel(const int* __restrict__ ei,
                                                    int* __restrict__ counts) {
    int idx = blockIdx.x * blockDim.x + threadIdx.x;
    int stride = gridDim.x * blockDim.x;
    for (int e = idx; e < TOT_EDGES; e += stride) {
        int d = (e < E_EDGES) ? ei[E_EDGES + e] : (e - E_EDGES);
        atomicAdd(&counts[d], 1);
    }
}

__global__ __launch_bounds__(256) void scan_partial(const int* __restrict__ counts,
                                                    int* __restrict__ partials) {
    __shared__ int s[256];
    int t = threadIdx.x;
    int i = blockIdx.x * 256 + t;
    s[t] = (i < N_NODES) ? counts[i] : 0;
    __syncthreads();
    for (int off = 128; off; off >>= 1) {
        if (t < off) s[t] += s[t + off];
        __syncthreads();
    }
    if (t == 0) partials[blockIdx.x] = s[0];
}

__global__ __launch_bounds__(512) void scan_partials_kernel(int* __restrict__ partials, int nb) {
    __shared__ int s[512];
    int t = threadIdx.x;
    int v = (t < nb) ? partials[t] : 0;
    s[t] = v;
    __syncthreads();
    for (int off = 1; off < 512; off <<= 1) {
        int y = (t >= off) ? s[t - off] : 0;
        __syncthreads();
        s[t] += y;
        __syncthreads();
    }
    if (t < nb) partials[t] = s[t] - v;
}

__global__ __launch_bounds__(256) void scan_final(const int* __restrict__ counts,
                                                  const int* __restrict__ partials,
                                                  int* __restrict__ row_ptr,
                                                  int* __restrict__ write_pos) {
    __shared__ int s[256];
    int t = threadIdx.x;
    int i = blockIdx.x * 256 + t;
    int v = (i < N_NODES) ? counts[i] : 0;
    s[t] = v;
    __syncthreads();
    for (int off = 1; off < 256; off <<= 1) {
        int y = (t >= off) ? s[t - off] : 0;
        __syncthreads();
        s[t] += y;
        __syncthreads();
    }
    int excl = s[t] - v;
    int rp = partials[blockIdx.x] + excl;
    if (i <= N_NODES) row_ptr[i] = rp;
    if (i < N_NODES) write_pos[i] = rp;
}

__global__ __launch_bounds__(256) void scatter_kernel(const int* __restrict__ ei,
                                                      int* __restrict__ write_pos,
                                                      int* __restrict__ src_sorted) {
    int idx = blockIdx.x * blockDim.x + threadIdx.x;
    int stride = gridDim.x * blockDim.x;
    for (int e = idx; e < TOT_EDGES; e += stride) {
        int srcv, d;
        if (e < E_EDGES) { srcv = ei[e]; d = ei[E_EDGES + e]; }
        else             { srcv = e - E_EDGES; d = srcv; }
        int p = atomicAdd(&write_pos[d], 1);
        src_sorted[p] = srcv;
    }
}

// ---------------------------------------------------------------------------
// Conversions
// ---------------------------------------------------------------------------

__global__ __launch_bounds__(256) void xconv(const float* __restrict__ x,
                                             unsigned short* __restrict__ hi,
                                             unsigned short* __restrict__ lo, int n) {
    int idx = blockIdx.x * blockDim.x + threadIdx.x;
    int stride = gridDim.x * blockDim.x;
    for (int i = idx; i < n; i += stride) {
        float v = x[i];
        unsigned short h = f2bf(v);
        hi[i] = h;
        lo[i] = f2bf(v - bf2f(h));
    }
}

__global__ __launch_bounds__(256) void wconv(const float* __restrict__ W,
                                             unsigned short* __restrict__ bth,
                                             unsigned short* __restrict__ btl,
                                             int K, int Nn, int Np) {
    int idx = blockIdx.x * blockDim.x + threadIdx.x;
    int total = Np * K;
    if (idx >= total) return;
    int n = idx / K, k = idx % K;
    float v = (n < Nn) ? W[k * Nn + n] : 0.f;
    unsigned short h = f2bf(v);
    bth[idx] = h;
    btl[idx] = f2bf(v - bf2f(h));
}

// ---------------------------------------------------------------------------
// Split-bf16 MFMA GEMM (hi*hi + hi*lo + lo*hi)
// ---------------------------------------------------------------------------
template<int K, int NTILES, int MWAVES, int NWAVES, int NACT, bool CFP32>
__global__ __launch_bounds__(256) void mfma_gemm(
    const unsigned short* __restrict__ Ahi, const unsigned short* __restrict__ Alo,
    const unsigned short* __restrict__ BThi, const unsigned short* __restrict__ BTlo,
    unsigned short* __restrict__ Chi, unsigned short* __restrict__ Clo,
    float* __restrict__ Cf, int M)
{
    int lane = threadIdx.x & 63;
    int wave = threadIdx.x >> 6;
    int quad = lane >> 4;
    int l16  = lane & 15;
    long mbase = (long)blockIdx.x * (64 * MWAVES) + (long)(wave / NWAVES) * 64;
    int n0 = (wave % NWAVES) * (NTILES * 16);

    const unsigned short* ah[4]; const unsigned short* al[4];
#pragma unroll
    for (int i = 0; i < 4; i++) {
        long r = mbase + i * 16 + l16;
        if (r > M - 1) r = M - 1;
        ah[i] = Ahi + r * K; al[i] = Alo + r * K;
    }
    const unsigned short* bh[NTILES]; const unsigned short* bl[NTILES];
#pragma unroll
    for (int j = 0; j < NTILES; j++) {
        long n = n0 + j * 16 + l16;
        bh[j] = BThi + n * K; bl[j] = BTlo + n * K;
    }
    const int ko = quad * 8;

    f32x4 acc[4][NTILES];
#pragma unroll
    for (int i = 0; i < 4; i++)
#pragma unroll
        for (int j = 0; j < NTILES; j++)
            acc[i][j] = (f32x4){0.f, 0.f, 0.f, 0.f};

    for (int k0 = 0; k0 < K; k0 += 32) {
        short8 vah[4], vall[4], vbh[NTILES], vbl[NTILES];
#pragma unroll
        for (int i = 0; i < 4; i++) {
            vah[i]  = *(const short8*)(ah[i] + k0 + ko);
            vall[i] = *(const short8*)(al[i] + k0 + ko);
        }
#pragma unroll
        for (int j = 0; j < NTILES; j++) {
            vbh[j] = *(const short8*)(bh[j] + k0 + ko);
            vbl[j] = *(const short8*)(bl[j] + k0 + ko);
        }
#pragma unroll
        for (int i = 0; i < 4; i++)
#pragma unroll
            for (int j = 0; j < NTILES; j++) {
                acc[i][j] = __builtin_amdgcn_mfma_f32_16x16x32_bf16(vah[i],  vbh[j], acc[i][j], 0, 0, 0);
                acc[i][j] = __builtin_amdgcn_mfma_f32_16x16x32_bf16(vah[i],  vbl[j], acc[i][j], 0, 0, 0);
                acc[i][j] = __builtin_amdgcn_mfma_f32_16x16x32_bf16(vall[i], vbh[j], acc[i][j], 0, 0, 0);
            }
    }

#pragma unroll
    for (int i = 0; i < 4; i++)
#pragma unroll
        for (int j = 0; j < NTILES; j++)
#pragma unroll
            for (int r = 0; r < 4; r++) {
                long row = mbase + i * 16 + quad * 4 + r;
                int col = n0 + j * 16 + l16;
                if (row < M && col < NACT) {
                    float v = acc[i][j][r];
                    if constexpr (CFP32) {
                        Cf[row * NACT + col] = v;
                    } else {
                        unsigned short h = f2bf(v);
                        Chi[row * NACT + col] = h;
                        Clo[row * NACT + col] = f2bf(v - bf2f(h));
                    }
                }
            }
}

// ---------------------------------------------------------------------------
// alpha_src / alpha_dst dot products (wave per node)
// ---------------------------------------------------------------------------
template<int F, bool FIN32>
__global__ __launch_bounds__(256) void row_dots(
    const unsigned short* __restrict__ hhi, const unsigned short* __restrict__ hlo,
    const float* __restrict__ hf,
    const float* __restrict__ a_s, const float* __restrict__ a_d,
    float* __restrict__ asrc, float* __restrict__ adst)
{
    int wave = threadIdx.x >> 6;
    int lane = threadIdx.x & 63;
    int node = blockIdx.x * 4 + wave;
    if (node >= N_NODES) return;
    float ps = 0.f, pd = 0.f;
    for (int f = lane; f < F; f += 64) {
        size_t idx = (size_t)node * F + f;
        float v;
        if constexpr (FIN32) v = hf[idx];
        else                 v = bf2f(hhi[idx]) + bf2f(hlo[idx]);
        ps += v * a_s[f];
        pd += v * a_d[f];
    }
#pragma unroll
    for (int off = 32; off; off >>= 1) {
        ps += __shfl_xor(ps, off);
        pd += __shfl_xor(pd, off);
    }
    if (lane == 0) {
        asrc[node] = ps;
        adst[node] = pd;
    }
}

// ---------------------------------------------------------------------------
// node_alpha: per-node segment softmax -> packed {src, alpha} per edge (CSR order)
// wave per node, lanes = edges. First chunk cached in registers.
// ---------------------------------------------------------------------------
__global__ __launch_bounds__(256) void node_alpha(
    const float* __restrict__ asrc, const float* __restrict__ adst,
    const int* __restrict__ row_ptr, const int* __restrict__ src_sorted,
    uint2* __restrict__ epair)
{
    int wave = threadIdx.x >> 6;
    int lane = threadIdx.x & 63;
    int node = blockIdx.x * 4 + wave;
    if (node >= N_NODES) return;
    int start = row_ptr[node];
    int end = row_ptr[node + 1];
    float ad = adst[node];

    int e0 = start + lane;
    int s_c = 0; float l_c = -1e30f;
    if (e0 < end) {
        s_c = src_sorted[e0];
        l_c = lrelu(asrc[s_c] + ad);
    }
    float m = l_c;
    for (int e = e0 + 64; e < end; e += 64) {
        int s = src_sorted[e];
        m = fmaxf(m, lrelu(asrc[s] + ad));
    }
#pragma unroll
    for (int off = 32; off; off >>= 1) m = fmaxf(m, __shfl_xor(m, off));

    float d = (e0 < end) ? __expf(l_c - m) : 0.f;
    for (int e = e0 + 64; e < end; e += 64) {
        int s = src_sorted[e];
        d += __expf(lrelu(asrc[s] + ad) - m);
    }
#pragma unroll
    for (int off = 32; off; off >>= 1) d += __shfl_xor(d, off);
    float inv = 1.0f / d;

    if (e0 < end)
        epair[e0] = make_uint2((unsigned)s_c, __float_as_uint(__expf(l_c - m) * inv));
    for (int e = e0 + 64; e < end; e += 64) {
        int s = src_sorted[e];
        float a = __expf(lrelu(asrc[s] + ad) - m) * inv;
        epair[e] = make_uint2((unsigned)s, __float_as_uint(a));
    }
}

// ---------------------------------------------------------------------------
// gat_agg2: weighted gather-aggregate with precomputed alphas.
// Wave per node; lanes split into edge groups of LPG lanes, each group loads a
// full feature row (16 B/lane). 2x software pipeline (2*EPW edges per iter).
//   bf16 path (G32=false): VEC=8 features/lane from hi plane.
//   fp32 path (G32=true):  VEC=4 features/lane.
// ---------------------------------------------------------------------------
template<int F, int LPG, bool G32, bool ACT, bool OSPLIT>
__global__ __launch_bounds__(256) void gat_agg2(
    const unsigned short* __restrict__ hbf, const float* __restrict__ hf,
    const uint2* __restrict__ epair, const int* __restrict__ row_ptr,
    const float* __restrict__ bias, const float* __restrict__ gamma,
    const float* __restrict__ beta, const float* __restrict__ rmean,
    const float* __restrict__ rvar,
    unsigned short* __restrict__ ohi, unsigned short* __restrict__ olo,
    float* __restrict__ outf)
{
    constexpr int EPW = 64 / LPG;           // edge groups per wave
    constexpr int VEC = G32 ? 4 : 8;        // features per lane (16 B)
    int wave = threadIdx.x >> 6;
    int lane = threadIdx.x & 63;
    int node = blockIdx.x * 4 + wave;
    if (node >= N_NODES) return;

    int start = row_ptr[node];
    int end = row_ptr[node + 1];
    int eg = lane / LPG;
    int fl = lane - eg * LPG;
    bool act = (eg < EPW);
    int f0 = fl * VEC;

    float acc[VEC];
#pragma unroll
    for (int v = 0; v < VEC; v++) acc[v] = 0.f;

    for (int cs = start; cs < end; cs += 2 * EPW) {
        int e1 = cs + eg;
        int e2 = cs + EPW + eg;
        float w1 = 0.f, w2 = 0.f;
        int s1 = 0, s2 = 0;
        if (act && e1 < end) { uint2 p = epair[e1]; s1 = (int)p.x; w1 = __uint_as_float(p.y); }
        if (act && e2 < end) { uint2 p = epair[e2]; s2 = (int)p.x; w2 = __uint_as_float(p.y); }
        if constexpr (G32) {
            float4 v1 = *reinterpret_cast<const float4*>(hf + (size_t)s1 * F + f0);
            float4 v2 = *reinterpret_cast<const float4*>(hf + (size_t)s2 * F + f0);
            acc[0] += w1 * v1.x; acc[1] += w1 * v1.y;
            acc[2] += w1 * v1.z; acc[3] += w1 * v1.w;
            acc[0] += w2 * v2.x; acc[1] += w2 * v2.y;
            acc[2] += w2 * v2.z; acc[3] += w2 * v2.w;
        } else {
            uint4 u1 = *reinterpret_cast<const uint4*>(hbf + (size_t)s1 * F + f0);
            uint4 u2 = *reinterpret_cast<const uint4*>(hbf + (size_t)s2 * F + f0);
            acc[0] += w1 * bflo(u1.x); acc[1] += w1 * bfhi(u1.x);
            acc[2] += w1 * bflo(u1.y); acc[3] += w1 * bfhi(u1.y);
            acc[4] += w1 * bflo(u1.z); acc[5] += w1 * bfhi(u1.z);
            acc[6] += w1 * bflo(u1.w); acc[7] += w1 * bfhi(u1.w);
            acc[0] += w2 * bflo(u2.x); acc[1] += w2 * bfhi(u2.x);
            acc[2] += w2 * bflo(u2.y); acc[3] += w2 * bfhi(u2.y);
            acc[4] += w2 * bflo(u2.z); acc[5] += w2 * bfhi(u2.z);
            acc[6] += w2 * bflo(u2.w); acc[7] += w2 * bfhi(u2.w);
        }
    }

    // combine edge groups onto group 0
    float tot[VEC];
    if constexpr (LPG == 32) {
#pragma unroll
        for (int v = 0; v < VEC; v++) tot[v] = acc[v] + __shfl_xor(acc[v], 32);
    } else if constexpr (LPG == 16) {
#pragma unroll
        for (int v = 0; v < VEC; v++) {
            float t = acc[v] + __shfl_xor(acc[v], 32);
            tot[v] = t + __shfl_xor(t, 16);
        }
    } else {  // LPG == 10, 6 groups, lanes 60-63 idle
#pragma unroll
        for (int v = 0; v < VEC; v++) tot[v] = acc[v];
#pragma unroll
        for (int g = 1; g < 6; g++)
#pragma unroll
            for (int v = 0; v < VEC; v++)
                tot[v] += __shfl(acc[v], fl + g * LPG);
    }

    if (eg == 0) {
#pragma unroll
        for (int v = 0; v < VEC; v++) {
            int f = f0 + v;
            float val = tot[v] + bias[f];
            if constexpr (ACT) {
                float rs = rsqrtf(rvar[f] + BN_EPS);
                val = tanhf((val - rmean[f]) * rs * gamma[f] + beta[f]);
            }
            size_t idx = (size_t)node * F + f;
            if constexpr (OSPLIT) {
                unsigned short h = f2bf(val);
                ohi[idx] = h;
                olo[idx] = f2bf(val - bf2f(h));
            } else {
                outf[idx] = val;
            }
        }
    }
}

// ---------------------------------------------------------------------------

static inline size_t align256(size_t x) { return (x + 255) & ~(size_t)255; }

extern "C" void kernel_launch(void* const* d_in, const int* in_sizes, int n_in,
                              void* d_out, int out_size, void* d_ws, size_t ws_size,
                              hipStream_t stream) {
    const float* x   = (const float*)d_in[0];
    const int* ei    = (const int*)d_in[1];
    const float* w1  = (const float*)d_in[2];
    const float* as1 = (const float*)d_in[3];
    const float* ad1 = (const float*)d_in[4];
    const float* b1  = (const float*)d_in[5];
    const float* g1  = (const float*)d_in[6];
    const float* be1 = (const float*)d_in[7];
    const float* rm1 = (const float*)d_in[8];
    const float* rv1 = (const float*)d_in[9];
    const float* w2  = (const float*)d_in[10];
    const float* as2 = (const float*)d_in[11];
    const float* ad2 = (const float*)d_in[12];
    const float* b2  = (const float*)d_in[13];
    const float* g2  = (const float*)d_in[14];
    const float* be2 = (const float*)d_in[15];
    const float* rm2 = (const float*)d_in[16];
    const float* rv2 = (const float*)d_in[17];
    const float* w3  = (const float*)d_in[18];
    const float* as3 = (const float*)d_in[19];
    const float* ad3 = (const float*)d_in[20];
    const float* b3  = (const float*)d_in[21];
    float* out = (float*)d_out;

    const size_t P128 = align256((size_t)N_NODES * 128 * 2);
    const size_t P256 = align256((size_t)N_NODES * 256 * 2);

    char* p = (char*)d_ws;
    char* regA = p; p += P256;   // xhi|xlo -> o1hi|o1lo -> o2hi
    char* regB = p; p += P256;   // h1hi -> h2hi -> h3f
    char* regC = p; p += P256;   // h1lo -> h2lo -> o2lo

    unsigned short* xhi  = (unsigned short*)regA;
    unsigned short* xlo  = (unsigned short*)(regA + P128);
    unsigned short* o1hi = xhi;
    unsigned short* o1lo = xlo;
    unsigned short* o2hi = (unsigned short*)regA;
    unsigned short* h1hi = (unsigned short*)regB;
    unsigned short* h2hi = (unsigned short*)regB;
    float*          h3f  = (float*)regB;
    unsigned short* h1lo = (unsigned short*)regC;
    unsigned short* h2lo = (unsigned short*)regC;
    unsigned short* o2lo = (unsigned short*)regC;

    float* asrc = (float*)p;  p += align256((size_t)N_NODES * 4);
    float* adst = (float*)p;  p += align256((size_t)N_NODES * 4);
    int* counts    = (int*)p; p += align256((size_t)N_NODES * 4);
    int* row_ptr   = (int*)p; p += align256((size_t)(N_NODES + 1) * 4);
    int* write_pos = (int*)p; p += align256((size_t)N_NODES * 4);
    int* src_sorted = (int*)p; p += align256((size_t)TOT_EDGES * 4);
    uint2* epair   = (uint2*)p; p += align256((size_t)TOT_EDGES * 8);
    int* partials  = (int*)p;  p += align256(512 * 4);
    unsigned short* w1th = (unsigned short*)p; p += align256(128 * 128 * 2);
    unsigned short* w1tl = (unsigned short*)p; p += align256(128 * 128 * 2);
    unsigned short* w2th = (unsigned short*)p; p += align256(256 * 128 * 2);
    unsigned short* w2tl = (unsigned short*)p; p += align256(256 * 128 * 2);
    unsigned short* w3th = (unsigned short*)p; p += align256(48 * 256 * 2);
    unsigned short* w3tl = (unsigned short*)p; p += align256(48 * 256 * 2);

    const int NB = (N_NODES + 255) / 256;

    xconv<<<4096, 256, 0, stream>>>(x, xhi, xlo, N_NODES * 128);
    wconv<<<(128 * 128 + 255) / 256, 256, 0, stream>>>(w1, w1th, w1tl, 128, 128, 128);
    wconv<<<(256 * 128 + 255) / 256, 256, 0, stream>>>(w2, w2th, w2tl, 128, 256, 256);
    wconv<<<(48 * 256 + 255) / 256, 256, 0, stream>>>(w3, w3th, w3tl, 256, 40, 48);

    hipMemsetAsync(counts, 0, (size_t)N_NODES * 4, stream);
    count_kernel<<<4096, 256, 0, stream>>>(ei, counts);
    scan_partial<<<NB, 256, 0, stream>>>(counts, partials);
    scan_partials_kernel<<<1, 512, 0, stream>>>(partials, NB);
    scan_final<<<NB, 256, 0, stream>>>(counts, partials, row_ptr, write_pos);
    scatter_kernel<<<4096, 256, 0, stream>>>(ei, write_pos, src_sorted);

    const int NWB = (N_NODES + 3) / 4;
    const int G64 = (N_NODES + 63) / 64;
    const int G256 = (N_NODES + 255) / 256;

    // --- Layer 1 ---
    mfma_gemm<128, 2, 1, 4, 128, false><<<G64, 256, 0, stream>>>(
        xhi, xlo, w1th, w1tl, h1hi, h1lo, nullptr, N_NODES);
    row_dots<128, false><<<NWB, 256, 0, stream>>>(h1hi, h1lo, nullptr, as1, ad1, asrc, adst);
    node_alpha<<<NWB, 256, 0, stream>>>(asrc, adst, row_ptr, src_sorted, epair);
    gat_agg2<128, 16, false, true, true><<<NWB, 256, 0, stream>>>(
        h1hi, nullptr, epair, row_ptr, b1, g1, be1, rm1, rv1, o1hi, o1lo, nullptr);

    // --- Layer 2 ---
    mfma_gemm<128, 4, 1, 4, 256, false><<<G64, 256, 0, stream>>>(
        o1hi, o1lo, w2th, w2tl, h2hi, h2lo, nullptr, N_NODES);
    row_dots<256, false><<<NWB, 256, 0, stream>>>(h2hi, h2lo, nullptr, as2, ad2, asrc, adst);
    node_alpha<<<NWB, 256, 0, stream>>>(asrc, adst, row_ptr, src_sorted, epair);
    gat_agg2<256, 32, false, true, true><<<NWB, 256, 0, stream>>>(
        h2hi, nullptr, epair, row_ptr, b2, g2, be2, rm2, rv2, o2hi, o2lo, nullptr);

    // --- Layer 3 ---
    mfma_gemm<256, 3, 4, 1, 40, true><<<G256, 256, 0, stream>>>(
        o2hi, o2lo, w3th, w3tl, nullptr, nullptr, h3f, N_NODES);
    row_dots<40, true><<<NWB, 256, 0, stream>>>(nullptr, nullptr, h3f, as3, ad3, asrc, adst);
    node_alpha<<<NWB, 256, 0, stream>>>(asrc, adst, row_ptr, src_sorted, epair);
    gat_agg2<40, 10, true, false, false><<<NWB, 256, 0, stream>>>(
        nullptr, h3f, epair, row_ptr, b3, b3, b3, b3, b3, nullptr, nullptr, out);
}

// Round 4
// 946.040 us; speedup vs baseline: 1.2521x; 1.2521x over previous
//
#include <hip/hip_runtime.h>
#include <hip/hip_bf16.h>
#include <cstddef>

#define N_NODES 100000
#define E_EDGES 1600000
#define TOT_EDGES (E_EDGES + N_NODES)
#define NEG_SLOPE 0.2f
#define BN_EPS 1e-5f

typedef __attribute__((ext_vector_type(8))) short short8;
typedef __attribute__((ext_vector_type(4))) float f32x4;

__device__ __forceinline__ unsigned short f2bf(float f) {
    union { float f; unsigned u; } c; c.f = f;
    unsigned u = c.u;
    u += 0x7fffu + ((u >> 16) & 1u);
    return (unsigned short)(u >> 16);
}
__device__ __forceinline__ float bf2f(unsigned short h) {
    union { unsigned u; float f; } c; c.u = ((unsigned)h) << 16;
    return c.f;
}
__device__ __forceinline__ float bflo(unsigned u) {
    union { unsigned u; float f; } c; c.u = u << 16; return c.f;
}
__device__ __forceinline__ float bfhi(unsigned u) {
    union { unsigned u; float f; } c; c.u = u & 0xffff0000u; return c.f;
}
__device__ __forceinline__ float lrelu(float t) {
    return (t > 0.f) ? t : NEG_SLOPE * t;
}

// ---------------------------------------------------------------------------
// CSR build
// ---------------------------------------------------------------------------

__global__ __launch_bounds__(256) void count_kernel(const int* __restrict__ ei,
                                                    int* __restrict__ counts) {
    int idx = blockIdx.x * blockDim.x + threadIdx.x;
    int stride = gridDim.x * blockDim.x;
    for (int e = idx; e < TOT_EDGES; e += stride) {
        int d = (e < E_EDGES) ? ei[E_EDGES + e] : (e - E_EDGES);
        atomicAdd(&counts[d], 1);
    }
}

__global__ __launch_bounds__(256) void scan_partial(const int* __restrict__ counts,
                                                    int* __restrict__ partials) {
    __shared__ int s[256];
    int t = threadIdx.x;
    int i = blockIdx.x * 256 + t;
    s[t] = (i < N_NODES) ? counts[i] : 0;
    __syncthreads();
    for (int off = 128; off; off >>= 1) {
        if (t < off) s[t] += s[t + off];
        __syncthreads();
    }
    if (t == 0) partials[blockIdx.x] = s[0];
}

__global__ __launch_bounds__(512) void scan_partials_kernel(int* __restrict__ partials, int nb) {
    __shared__ int s[512];
    int t = threadIdx.x;
    int v = (t < nb) ? partials[t] : 0;
    s[t] = v;
    __syncthreads();
    for (int off = 1; off < 512; off <<= 1) {
        int y = (t >= off) ? s[t - off] : 0;
        __syncthreads();
        s[t] += y;
        __syncthreads();
    }
    if (t < nb) partials[t] = s[t] - v;
}

__global__ __launch_bounds__(256) void scan_final(const int* __restrict__ counts,
                                                  const int* __restrict__ partials,
                                                  int* __restrict__ row_ptr,
                                                  int* __restrict__ write_pos) {
    __shared__ int s[256];
    int t = threadIdx.x;
    int i = blockIdx.x * 256 + t;
    int v = (i < N_NODES) ? counts[i] : 0;
    s[t] = v;
    __syncthreads();
    for (int off = 1; off < 256; off <<= 1) {
        int y = (t >= off) ? s[t - off] : 0;
        __syncthreads();
        s[t] += y;
        __syncthreads();
    }
    int excl = s[t] - v;
    int rp = partials[blockIdx.x] + excl;
    if (i <= N_NODES) row_ptr[i] = rp;
    if (i < N_NODES) write_pos[i] = rp;
}

__global__ __launch_bounds__(256) void scatter_kernel(const int* __restrict__ ei,
                                                      int* __restrict__ write_pos,
                                                      int* __restrict__ src_sorted) {
    int idx = blockIdx.x * blockDim.x + threadIdx.x;
    int stride = gridDim.x * blockDim.x;
    for (int e = idx; e < TOT_EDGES; e += stride) {
        int srcv, d;
        if (e < E_EDGES) { srcv = ei[e]; d = ei[E_EDGES + e]; }
        else             { srcv = e - E_EDGES; d = srcv; }
        int p = atomicAdd(&write_pos[d], 1);
        src_sorted[p] = srcv;
    }
}

// ---------------------------------------------------------------------------
// Conversions
// ---------------------------------------------------------------------------

__global__ __launch_bounds__(256) void xconv(const float* __restrict__ x,
                                             unsigned short* __restrict__ hi,
                                             unsigned short* __restrict__ lo, int n) {
    int idx = blockIdx.x * blockDim.x + threadIdx.x;
    int stride = gridDim.x * blockDim.x;
    for (int i = idx; i < n; i += stride) {
        float v = x[i];
        unsigned short h = f2bf(v);
        hi[i] = h;
        lo[i] = f2bf(v - bf2f(h));
    }
}

__global__ __launch_bounds__(256) void wconv(const float* __restrict__ W,
                                             unsigned short* __restrict__ bth,
                                             unsigned short* __restrict__ btl,
                                             int K, int Nn, int Np) {
    int idx = blockIdx.x * blockDim.x + threadIdx.x;
    int total = Np * K;
    if (idx >= total) return;
    int n = idx / K, k = idx % K;
    float v = (n < Nn) ? W[k * Nn + n] : 0.f;
    unsigned short h = f2bf(v);
    bth[idx] = h;
    btl[idx] = f2bf(v - bf2f(h));
}

// ---------------------------------------------------------------------------
// Split-bf16 MFMA GEMM (hi*hi + hi*lo + lo*hi)
// ---------------------------------------------------------------------------
template<int K, int NTILES, int MWAVES, int NWAVES, int NACT, bool CFP32>
__global__ __launch_bounds__(256) void mfma_gemm(
    const unsigned short* __restrict__ Ahi, const unsigned short* __restrict__ Alo,
    const unsigned short* __restrict__ BThi, const unsigned short* __restrict__ BTlo,
    unsigned short* __restrict__ Chi, unsigned short* __restrict__ Clo,
    float* __restrict__ Cf, int M)
{
    int lane = threadIdx.x & 63;
    int wave = threadIdx.x >> 6;
    int quad = lane >> 4;
    int l16  = lane & 15;
    long mbase = (long)blockIdx.x * (64 * MWAVES) + (long)(wave / NWAVES) * 64;
    int n0 = (wave % NWAVES) * (NTILES * 16);

    const unsigned short* ah[4]; const unsigned short* al[4];
#pragma unroll
    for (int i = 0; i < 4; i++) {
        long r = mbase + i * 16 + l16;
        if (r > M - 1) r = M - 1;
        ah[i] = Ahi + r * K; al[i] = Alo + r * K;
    }
    const unsigned short* bh[NTILES]; const unsigned short* bl[NTILES];
#pragma unroll
    for (int j = 0; j < NTILES; j++) {
        long n = n0 + j * 16 + l16;
        bh[j] = BThi + n * K; bl[j] = BTlo + n * K;
    }
    const int ko = quad * 8;

    f32x4 acc[4][NTILES];
#pragma unroll
    for (int i = 0; i < 4; i++)
#pragma unroll
        for (int j = 0; j < NTILES; j++)
            acc[i][j] = (f32x4){0.f, 0.f, 0.f, 0.f};

    for (int k0 = 0; k0 < K; k0 += 32) {
        short8 vah[4], vall[4], vbh[NTILES], vbl[NTILES];
#pragma unroll
        for (int i = 0; i < 4; i++) {
            vah[i]  = *(const short8*)(ah[i] + k0 + ko);
            vall[i] = *(const short8*)(al[i] + k0 + ko);
        }
#pragma unroll
        for (int j = 0; j < NTILES; j++) {
            vbh[j] = *(const short8*)(bh[j] + k0 + ko);
            vbl[j] = *(const short8*)(bl[j] + k0 + ko);
        }
#pragma unroll
        for (int i = 0; i < 4; i++)
#pragma unroll
            for (int j = 0; j < NTILES; j++) {
                acc[i][j] = __builtin_amdgcn_mfma_f32_16x16x32_bf16(vah[i],  vbh[j], acc[i][j], 0, 0, 0);
                acc[i][j] = __builtin_amdgcn_mfma_f32_16x16x32_bf16(vah[i],  vbl[j], acc[i][j], 0, 0, 0);
                acc[i][j] = __builtin_amdgcn_mfma_f32_16x16x32_bf16(vall[i], vbh[j], acc[i][j], 0, 0, 0);
            }
    }

#pragma unroll
    for (int i = 0; i < 4; i++)
#pragma unroll
        for (int j = 0; j < NTILES; j++)
#pragma unroll
            for (int r = 0; r < 4; r++) {
                long row = mbase + i * 16 + quad * 4 + r;
                int col = n0 + j * 16 + l16;
                if (row < M && col < NACT) {
                    float v = acc[i][j][r];
                    if constexpr (CFP32) {
                        Cf[row * NACT + col] = v;
                    } else {
                        unsigned short h = f2bf(v);
                        Chi[row * NACT + col] = h;
                        Clo[row * NACT + col] = f2bf(v - bf2f(h));
                    }
                }
            }
}

// ---------------------------------------------------------------------------
// alpha_src / alpha_dst dot products (wave per node)
// ---------------------------------------------------------------------------
template<int F, bool FIN32>
__global__ __launch_bounds__(256) void row_dots(
    const unsigned short* __restrict__ hhi, const unsigned short* __restrict__ hlo,
    const float* __restrict__ hf,
    const float* __restrict__ a_s, const float* __restrict__ a_d,
    float* __restrict__ asrc, float* __restrict__ adst)
{
    int wave = threadIdx.x >> 6;
    int lane = threadIdx.x & 63;
    int node = blockIdx.x * 4 + wave;
    if (node >= N_NODES) return;
    float ps = 0.f, pd = 0.f;
    for (int f = lane; f < F; f += 64) {
        size_t idx = (size_t)node * F + f;
        float v;
        if constexpr (FIN32) v = hf[idx];
        else                 v = bf2f(hhi[idx]) + bf2f(hlo[idx]);
        ps += v * a_s[f];
        pd += v * a_d[f];
    }
#pragma unroll
    for (int off = 32; off; off >>= 1) {
        ps += __shfl_xor(ps, off);
        pd += __shfl_xor(pd, off);
    }
    if (lane == 0) {
        asrc[node] = ps;
        adst[node] = pd;
    }
}

// ---------------------------------------------------------------------------
// node_alpha: per-node segment softmax -> packed {src, alpha} per edge
// ---------------------------------------------------------------------------
__global__ __launch_bounds__(256) void node_alpha(
    const float* __restrict__ asrc, const float* __restrict__ adst,
    const int* __restrict__ row_ptr, const int* __restrict__ src_sorted,
    uint2* __restrict__ epair)
{
    int wave = threadIdx.x >> 6;
    int lane = threadIdx.x & 63;
    int node = blockIdx.x * 4 + wave;
    if (node >= N_NODES) return;
    int start = row_ptr[node];
    int end = row_ptr[node + 1];
    float ad = adst[node];

    int e0 = start + lane;
    int s_c = 0; float l_c = -1e30f;
    if (e0 < end) {
        s_c = src_sorted[e0];
        l_c = lrelu(asrc[s_c] + ad);
    }
    float m = l_c;
    for (int e = e0 + 64; e < end; e += 64) {
        int s = src_sorted[e];
        m = fmaxf(m, lrelu(asrc[s] + ad));
    }
#pragma unroll
    for (int off = 32; off; off >>= 1) m = fmaxf(m, __shfl_xor(m, off));

    float d = (e0 < end) ? __expf(l_c - m) : 0.f;
    for (int e = e0 + 64; e < end; e += 64) {
        int s = src_sorted[e];
        d += __expf(lrelu(asrc[s] + ad) - m);
    }
#pragma unroll
    for (int off = 32; off; off >>= 1) d += __shfl_xor(d, off);
    float inv = 1.0f / d;

    if (e0 < end)
        epair[e0] = make_uint2((unsigned)s_c, __float_as_uint(__expf(l_c - m) * inv));
    for (int e = e0 + 64; e < end; e += 64) {
        int s = src_sorted[e];
        float a = __expf(lrelu(asrc[s] + ad) - m) * inv;
        epair[e] = make_uint2((unsigned)s, __float_as_uint(a));
    }
}

// ---------------------------------------------------------------------------
// gat_agg3: wave per node. {src, alpha} loaded once per 64-edge chunk into
// registers; inner loop broadcasts via v_readlane (SGPR index, no bpermute),
// giving an SGPR row base -> one coalesced scalar-base load per edge, alpha
// as a uniform FMA operand. Unroll x4 for loads-in-flight.
// ---------------------------------------------------------------------------
template<int F, bool G32>
__device__ __forceinline__ void agg_step(const unsigned short* __restrict__ hbf,
                                         const float* __restrict__ hf,
                                         int ss, int wb, int lane, float* acc) {
    float ww = __int_as_float(wb);
    if constexpr (G32) {
        acc[0] += ww * hf[(size_t)ss * F + lane];  // lanes >= F accumulate garbage, never written
    } else if constexpr (F == 256) {
        uint2 u = *reinterpret_cast<const uint2*>(hbf + (size_t)ss * F + lane * 4);
        acc[0] += ww * bflo(u.x); acc[1] += ww * bfhi(u.x);
        acc[2] += ww * bflo(u.y); acc[3] += ww * bfhi(u.y);
    } else {  // F == 128
        unsigned u = *reinterpret_cast<const unsigned*>(hbf + (size_t)ss * F + lane * 2);
        acc[0] += ww * bflo(u); acc[1] += ww * bfhi(u);
    }
}

template<int F, bool G32, bool ACT, bool OSPLIT>
__global__ __launch_bounds__(256) void gat_agg3(
    const unsigned short* __restrict__ hbf, const float* __restrict__ hf,
    const uint2* __restrict__ epair, const int* __restrict__ row_ptr,
    const float* __restrict__ bias, const float* __restrict__ gamma,
    const float* __restrict__ beta, const float* __restrict__ rmean,
    const float* __restrict__ rvar,
    unsigned short* __restrict__ ohi, unsigned short* __restrict__ olo,
    float* __restrict__ outf)
{
    constexpr int NA = G32 ? 1 : (F / 64);  // floats per lane
    int wave = threadIdx.x >> 6;
    int lane = threadIdx.x & 63;
    int node = blockIdx.x * 4 + wave;
    if (node >= N_NODES) return;

    int start = row_ptr[node];
    int end = row_ptr[node + 1];

    float acc[NA];
#pragma unroll
    for (int v = 0; v < NA; v++) acc[v] = 0.f;

    int sv = 0, wv = 0;
    {
        int e = start + lane;
        if (e < end) { uint2 p = epair[e]; sv = (int)p.x; wv = (int)p.y; }
    }

    for (int cs = start; cs < end; cs += 64) {
        int cnt = min(64, end - cs);
        // prefetch next chunk's {src, alpha}
        int nsv = 0, nwv = 0;
        int en = cs + 64 + lane;
        if (en < end) { uint2 p = epair[en]; nsv = (int)p.x; nwv = (int)p.y; }

        int j = 0;
        for (; j + 4 <= cnt; j += 4) {
#pragma unroll
            for (int k = 0; k < 4; k++) {
                int ss = __builtin_amdgcn_readlane(sv, j + k);
                int wb = __builtin_amdgcn_readlane(wv, j + k);
                agg_step<F, G32>(hbf, hf, ss, wb, lane, acc);
            }
        }
        for (; j < cnt; j++) {
            int ss = __builtin_amdgcn_readlane(sv, j);
            int wb = __builtin_amdgcn_readlane(wv, j);
            agg_step<F, G32>(hbf, hf, ss, wb, lane, acc);
        }
        sv = nsv; wv = nwv;
    }

    if (G32 && lane >= F) return;
#pragma unroll
    for (int v = 0; v < NA; v++) {
        int f = G32 ? lane : lane * NA + v;
        float val = acc[v] + bias[f];
        if constexpr (ACT) {
            float rs = rsqrtf(rvar[f] + BN_EPS);
            val = tanhf((val - rmean[f]) * rs * gamma[f] + beta[f]);
        }
        size_t idx = (size_t)node * F + f;
        if constexpr (OSPLIT) {
            unsigned short h = f2bf(val);
            ohi[idx] = h;
            olo[idx] = f2bf(val - bf2f(h));
        } else {
            outf[idx] = val;
        }
    }
}

// ---------------------------------------------------------------------------

static inline size_t align256(size_t x) { return (x + 255) & ~(size_t)255; }

extern "C" void kernel_launch(void* const* d_in, const int* in_sizes, int n_in,
                              void* d_out, int out_size, void* d_ws, size_t ws_size,
                              hipStream_t stream) {
    const float* x   = (const float*)d_in[0];
    const int* ei    = (const int*)d_in[1];
    const float* w1  = (const float*)d_in[2];
    const float* as1 = (const float*)d_in[3];
    const float* ad1 = (const float*)d_in[4];
    const float* b1  = (const float*)d_in[5];
    const float* g1  = (const float*)d_in[6];
    const float* be1 = (const float*)d_in[7];
    const float* rm1 = (const float*)d_in[8];
    const float* rv1 = (const float*)d_in[9];
    const float* w2  = (const float*)d_in[10];
    const float* as2 = (const float*)d_in[11];
    const float* ad2 = (const float*)d_in[12];
    const float* b2  = (const float*)d_in[13];
    const float* g2  = (const float*)d_in[14];
    const float* be2 = (const float*)d_in[15];
    const float* rm2 = (const float*)d_in[16];
    const float* rv2 = (const float*)d_in[17];
    const float* w3  = (const float*)d_in[18];
    const float* as3 = (const float*)d_in[19];
    const float* ad3 = (const float*)d_in[20];
    const float* b3  = (const float*)d_in[21];
    float* out = (float*)d_out;

    const size_t P128 = align256((size_t)N_NODES * 128 * 2);
    const size_t P256 = align256((size_t)N_NODES * 256 * 2);

    char* p = (char*)d_ws;
    char* regA = p; p += P256;   // xhi|xlo -> o1hi|o1lo -> o2hi
    char* regB = p; p += P256;   // h1hi -> h2hi -> h3f
    char* regC = p; p += P256;   // h1lo -> h2lo -> o2lo

    unsigned short* xhi  = (unsigned short*)regA;
    unsigned short* xlo  = (unsigned short*)(regA + P128);
    unsigned short* o1hi = xhi;
    unsigned short* o1lo = xlo;
    unsigned short* o2hi = (unsigned short*)regA;
    unsigned short* h1hi = (unsigned short*)regB;
    unsigned short* h2hi = (unsigned short*)regB;
    float*          h3f  = (float*)regB;
    unsigned short* h1lo = (unsigned short*)regC;
    unsigned short* h2lo = (unsigned short*)regC;
    unsigned short* o2lo = (unsigned short*)regC;

    float* asrc = (float*)p;  p += align256((size_t)N_NODES * 4);
    float* adst = (float*)p;  p += align256((size_t)N_NODES * 4);
    int* counts    = (int*)p; p += align256((size_t)N_NODES * 4);
    int* row_ptr   = (int*)p; p += align256((size_t)(N_NODES + 1) * 4);
    int* write_pos = (int*)p; p += align256((size_t)N_NODES * 4);
    int* src_sorted = (int*)p; p += align256((size_t)TOT_EDGES * 4);
    uint2* epair   = (uint2*)p; p += align256((size_t)TOT_EDGES * 8);
    int* partials  = (int*)p;  p += align256(512 * 4);
    unsigned short* w1th = (unsigned short*)p; p += align256(128 * 128 * 2);
    unsigned short* w1tl = (unsigned short*)p; p += align256(128 * 128 * 2);
    unsigned short* w2th = (unsigned short*)p; p += align256(256 * 128 * 2);
    unsigned short* w2tl = (unsigned short*)p; p += align256(256 * 128 * 2);
    unsigned short* w3th = (unsigned short*)p; p += align256(48 * 256 * 2);
    unsigned short* w3tl = (unsigned short*)p; p += align256(48 * 256 * 2);

    const int NB = (N_NODES + 255) / 256;

    xconv<<<4096, 256, 0, stream>>>(x, xhi, xlo, N_NODES * 128);
    wconv<<<(128 * 128 + 255) / 256, 256, 0, stream>>>(w1, w1th, w1tl, 128, 128, 128);
    wconv<<<(256 * 128 + 255) / 256, 256, 0, stream>>>(w2, w2th, w2tl, 128, 256, 256);
    wconv<<<(48 * 256 + 255) / 256, 256, 0, stream>>>(w3, w3th, w3tl, 256, 40, 48);

    hipMemsetAsync(counts, 0, (size_t)N_NODES * 4, stream);
    count_kernel<<<4096, 256, 0, stream>>>(ei, counts);
    scan_partial<<<NB, 256, 0, stream>>>(counts, partials);
    scan_partials_kernel<<<1, 512, 0, stream>>>(partials, NB);
    scan_final<<<NB, 256, 0, stream>>>(counts, partials, row_ptr, write_pos);
    scatter_kernel<<<4096, 256, 0, stream>>>(ei, write_pos, src_sorted);

    const int NWB = (N_NODES + 3) / 4;
    const int G64 = (N_NODES + 63) / 64;
    const int G256 = (N_NODES + 255) / 256;

    // --- Layer 1 ---
    mfma_gemm<128, 2, 1, 4, 128, false><<<G64, 256, 0, stream>>>(
        xhi, xlo, w1th, w1tl, h1hi, h1lo, nullptr, N_NODES);
    row_dots<128, false><<<NWB, 256, 0, stream>>>(h1hi, h1lo, nullptr, as1, ad1, asrc, adst);
    node_alpha<<<NWB, 256, 0, stream>>>(asrc, adst, row_ptr, src_sorted, epair);
    gat_agg3<128, false, true, true><<<NWB, 256, 0, stream>>>(
        h1hi, nullptr, epair, row_ptr, b1, g1, be1, rm1, rv1, o1hi, o1lo, nullptr);

    // --- Layer 2 ---
    mfma_gemm<128, 4, 1, 4, 256, false><<<G64, 256, 0, stream>>>(
        o1hi, o1lo, w2th, w2tl, h2hi, h2lo, nullptr, N_NODES);
    row_dots<256, false><<<NWB, 256, 0, stream>>>(h2hi, h2lo, nullptr, as2, ad2, asrc, adst);
    node_alpha<<<NWB, 256, 0, stream>>>(asrc, adst, row_ptr, src_sorted, epair);
    gat_agg3<256, false, true, true><<<NWB, 256, 0, stream>>>(
        h2hi, nullptr, epair, row_ptr, b2, g2, be2, rm2, rv2, o2hi, o2lo, nullptr);

    // --- Layer 3 ---
    mfma_gemm<256, 3, 4, 1, 40, true><<<G256, 256, 0, stream>>>(
        o2hi, o2lo, w3th, w3tl, nullptr, nullptr, h3f, N_NODES);
    row_dots<40, true><<<NWB, 256, 0, stream>>>(nullptr, nullptr, h3f, as3, ad3, asrc, adst);
    node_alpha<<<NWB, 256, 0, stream>>>(asrc, adst, row_ptr, src_sorted, epair);
    gat_agg3<40, true, false, false><<<NWB, 256, 0, stream>>>(
        nullptr, h3f, epair, row_ptr, b3, b3, b3, b3, b3, nullptr, nullptr, out);
}